// Round 1
// baseline (828.751 us; speedup 1.0000x reference)
//
#include <hip/hip_runtime.h>
#include <hip/hip_bf16.h>

#define N_NODES 131072
#define N_EDGES 2097152
#define NB 64
#define N_PER 2048
#define IN_CH 128
#define HID 32

__device__ __forceinline__ float leaky01(float v) { return v >= 0.0f ? v : 0.01f * v; }
__device__ __forceinline__ float leaky2(float v)  { return v >= 0.0f ? v : 0.2f  * v; }

// ---------------- embed: h = x @ w_embed + b_embed ----------------
__global__ void k_embed(const float* __restrict__ x, const float* __restrict__ W,
                        const float* __restrict__ bias, float* __restrict__ h) {
    __shared__ float sW[IN_CH * HID];   // 16 KB
    __shared__ float sx[8 * IN_CH];     // 4 KB
    int tid = threadIdx.x;
    for (int i = tid; i < IN_CH * HID; i += 256) sW[i] = W[i];
    int base = blockIdx.x * 8 * IN_CH;
    for (int i = tid; i < 8 * IN_CH; i += 256) sx[i] = x[base + i];
    __syncthreads();
    int r = tid >> 5, c = tid & 31;
    float acc = bias[c];
    #pragma unroll
    for (int k = 0; k < IN_CH; ++k) acc += sx[r * IN_CH + k] * sW[k * HID + c];
    h[(blockIdx.x * 8 + r) * HID + c] = acc;
}

// ---------------- CSR build ----------------
__global__ void k_count(const int* __restrict__ ei, int* __restrict__ cnt) {
    int e = blockIdx.x * 256 + threadIdx.x;
    atomicAdd(&cnt[ei[N_EDGES + e]], 1);
}

__global__ void k_scan1(const int* __restrict__ cnt, int* __restrict__ rp, int* __restrict__ bs) {
    __shared__ int s[256];
    int tid = threadIdx.x;
    int gid = blockIdx.x * 256 + tid;
    int v = cnt[gid];
    s[tid] = v; __syncthreads();
    for (int off = 1; off < 256; off <<= 1) {
        int t = (tid >= off) ? s[tid - off] : 0;
        __syncthreads();
        s[tid] += t;
        __syncthreads();
    }
    rp[gid] = s[tid] - v;           // exclusive within block
    if (tid == 255) bs[blockIdx.x] = s[255];
}

__global__ void k_scan2(int* __restrict__ bs) {
    __shared__ int s[512];
    int tid = threadIdx.x;
    int v = bs[tid];
    s[tid] = v; __syncthreads();
    for (int off = 1; off < 512; off <<= 1) {
        int t = (tid >= off) ? s[tid - off] : 0;
        __syncthreads();
        s[tid] += t;
        __syncthreads();
    }
    bs[tid] = s[tid] - v;           // exclusive block offsets
}

__global__ void k_scan3(int* __restrict__ rp, const int* __restrict__ bs, int* __restrict__ cur) {
    int gid = blockIdx.x * 256 + threadIdx.x;
    int v = rp[gid] + bs[blockIdx.x];
    rp[gid] = v;
    cur[gid] = v;
    if (gid == 0) rp[N_NODES] = N_EDGES;
}

__global__ void k_fill(const int* __restrict__ ei, int* __restrict__ cur, int* __restrict__ esrc) {
    int e = blockIdx.x * 256 + threadIdx.x;
    int d = ei[N_EDGES + e];
    int s = ei[e];
    int pos = atomicAdd(&cur[d], 1);
    esrc[pos] = s;
}

// ------- GAT pre: t = leaky(BN(h)); g = t@W; as = g@a_src; ad = g@a_dst -------
__global__ void k_gat_pre(const float* __restrict__ h, const float* __restrict__ W,
                          const float* __restrict__ a_src, const float* __restrict__ a_dst,
                          const float* __restrict__ bn_g, const float* __restrict__ bn_b,
                          const float* __restrict__ bn_m, const float* __restrict__ bn_v,
                          float* __restrict__ g, float* __restrict__ asv, float* __restrict__ adv) {
    __shared__ float sW[HID * HID];
    __shared__ float st[8 * HID];
    __shared__ float ssc[HID], ssh[HID];
    int tid = threadIdx.x;
    if (tid < HID) {
        float sc = bn_g[tid] * rsqrtf(bn_v[tid] + 1e-5f);
        ssc[tid] = sc;
        ssh[tid] = bn_b[tid] - bn_m[tid] * sc;
    }
    for (int i = tid; i < HID * HID; i += 256) sW[i] = W[i];
    __syncthreads();
    int base = blockIdx.x * 8 * HID;
    {
        int c = tid & 31;
        float v = h[base + tid];
        v = v * ssc[c] + ssh[c];
        st[tid] = leaky01(v);
    }
    __syncthreads();
    int r = tid >> 5, c = tid & 31;
    float acc = 0.0f;
    #pragma unroll
    for (int k = 0; k < HID; ++k) acc += st[r * HID + k] * sW[k * HID + c];
    g[base + tid] = acc;
    float p = acc * a_src[c];
    #pragma unroll
    for (int m = 16; m >= 1; m >>= 1) p += __shfl_xor(p, m);
    float q = acc * a_dst[c];
    #pragma unroll
    for (int m = 16; m >= 1; m >>= 1) q += __shfl_xor(q, m);
    if (c == 0) {
        int row = blockIdx.x * 8 + r;
        asv[row] = p;
        adv[row] = q;
    }
}

// ------- GAT aggregate: online segment softmax + weighted sum, residual -------
__global__ void k_aggr(float* __restrict__ h, const float* __restrict__ g,
                       const float* __restrict__ asv, const float* __restrict__ adv,
                       const int* __restrict__ rp, const int* __restrict__ esrc,
                       const float* __restrict__ gb) {
    int node = blockIdx.x * 8 + (threadIdx.x >> 5);
    int c = threadIdx.x & 31;
    float ad_i = adv[node];
    // self-loop initializes the running softmax state
    float m = leaky2(asv[node] + ad_i);
    float z = 1.0f;
    float acc = g[node * HID + c];
    int beg = rp[node], end = rp[node + 1];
    for (int j = beg; j < end; ++j) {
        int s = esrc[j];
        float lg = leaky2(asv[s] + ad_i);
        float gs = g[s * HID + c];
        if (lg > m) {
            float sc = __expf(m - lg);
            z = z * sc + 1.0f;
            acc = acc * sc + gs;
            m = lg;
        } else {
            float e = __expf(lg - m);
            z += e;
            acc += e * gs;
        }
    }
    h[node * HID + c] += acc / (z + 1e-16f) + gb[c];
}

// ------- mem_pool 1: S1 [N,10], colsum [B,10], xo partial [B,10,32] -------
__global__ void k_mem1(const float* __restrict__ h, const float* __restrict__ k1,
                       const float* __restrict__ conv_w,
                       float* __restrict__ S1, float* __restrict__ xo,
                       float* __restrict__ colsum) {
    __shared__ float sk1[5 * 10 * HID];   // 6400 B
    __shared__ float sk2[50];
    __shared__ float scw[5];
    __shared__ float s1l[256][10];        // 10240 B
    int tid = threadIdx.x;
    for (int i = tid; i < 5 * 10 * HID; i += 256) sk1[i] = k1[i];
    if (tid < 5) scw[tid] = conv_w[tid];
    __syncthreads();
    if (tid < 50) {
        float s = 0.0f;
        for (int f = 0; f < HID; ++f) { float t = sk1[tid * HID + f]; s += t * t; }
        sk2[tid] = s;
    }
    __syncthreads();

    int nid = blockIdx.x * 256 + tid;
    float xr[HID];
    const float4* xp = (const float4*)(h + nid * HID);
    #pragma unroll
    for (int i = 0; i < 8; ++i) {
        float4 v = xp[i];
        xr[4 * i] = v.x; xr[4 * i + 1] = v.y; xr[4 * i + 2] = v.z; xr[4 * i + 3] = v.w;
    }
    float x2n = 0.0f;
    #pragma unroll
    for (int f = 0; f < HID; ++f) x2n += xr[f] * xr[f];

    float Sc[10];
    #pragma unroll
    for (int k = 0; k < 10; ++k) Sc[k] = 0.0f;

    for (int hh = 0; hh < 5; ++hh) {
        float tmp[10];
        float rsum = 0.0f;
        #pragma unroll
        for (int k = 0; k < 10; ++k) {
            float dot = 0.0f;
            #pragma unroll
            for (int f = 0; f < HID; ++f) dot += xr[f] * sk1[(hh * 10 + k) * HID + f];
            float d = x2n + sk2[hh * 10 + k] - 2.0f * dot;
            d = d > 0.0f ? d : 0.0f;
            float s = 1.0f / (1.0f + d);      // student-t, tau=1 -> exponent -1
            tmp[k] = s;
            rsum += s;
        }
        float w = scw[hh] / rsum;
        #pragma unroll
        for (int k = 0; k < 10; ++k) Sc[k] += tmp[k] * w;
    }
    // softmax over k
    float mx = Sc[0];
    #pragma unroll
    for (int k = 1; k < 10; ++k) mx = fmaxf(mx, Sc[k]);
    float se = 0.0f;
    #pragma unroll
    for (int k = 0; k < 10; ++k) { float e = __expf(Sc[k] - mx); Sc[k] = e; se += e; }
    float inv = 1.0f / se;
    #pragma unroll
    for (int k = 0; k < 10; ++k) {
        float v = Sc[k] * inv;
        Sc[k] = v;
        s1l[tid][k] = v;
        S1[nid * 10 + k] = v;
    }
    __syncthreads();

    int b = nid >> 11;
    // xo[b][k][f] partial over this block's 256 nodes
    for (int idx = tid; idx < 320; idx += 256) {
        int k = idx >> 5, f = idx & 31;
        float s = 0.0f;
        const float* xb = h + (blockIdx.x * 256) * HID + f;
        for (int n = 0; n < 256; ++n) s += s1l[n][k] * xb[n * HID];
        atomicAdd(&xo[(b * 10 + k) * HID + f], s);
    }
    for (int k = tid; k < 10; k += 256) {
        float s = 0.0f;
        for (int n = 0; n < 256; ++n) s += s1l[n][k];
        atomicAdd(&colsum[b * 10 + k], s);
    }
}

// ------- kl_loss(S1) accumulation -------
__global__ void k_kl(const float* __restrict__ S1, const float* __restrict__ colsum,
                     float* __restrict__ klg) {
    __shared__ float red[256];
    int tid = threadIdx.x;
    int nid = blockIdx.x * 256 + tid;
    int b = nid >> 11;
    const float* srow = S1 + nid * 10;
    float p[10], sv[10];
    float dsum = 0.0f;
    #pragma unroll
    for (int k = 0; k < 10; ++k) {
        float s = srow[k];
        sv[k] = s;
        float pk = s * s / fmaxf(colsum[b * 10 + k], 1e-15f);
        p[k] = pk;
        dsum += pk;
    }
    float invd = 1.0f / dsum;   // row-sum of S1 is 1 (softmax), never 0
    float term = 0.0f;
    #pragma unroll
    for (int k = 0; k < 10; ++k) {
        float pk = fmaxf(p[k] * invd, 1e-15f);
        float s = fmaxf(sv[k], 1e-15f);
        term += pk * (logf(pk) - logf(s));
    }
    red[tid] = term; __syncthreads();
    for (int off = 128; off > 0; off >>= 1) {
        if (tid < off) red[tid] += red[tid + off];
        __syncthreads();
    }
    if (tid == 0) atomicAdd(klg, red[0]);
}

// ------- head: x1 = xo@lin1 + b; mem_pool2 collapses (S2 == ones, kl2 == 0) -------
__global__ void k_head(const float* __restrict__ xo, const float* __restrict__ l1w,
                       const float* __restrict__ l1b, const float* __restrict__ l2w,
                       const float* __restrict__ l2b, const float* __restrict__ klg,
                       float* __restrict__ out) {
    __shared__ float sxo[320];
    __shared__ float s80[80];
    __shared__ float lg[10];
    int b = blockIdx.x, tid = threadIdx.x;
    for (int i = tid; i < 320; i += 128) sxo[i] = xo[b * 320 + i];
    __syncthreads();
    if (tid < 80) {
        float s = 0.0f;
        for (int k = 0; k < 10; ++k) {
            float a = l1b[tid];
            #pragma unroll
            for (int i = 0; i < HID; ++i) a += sxo[k * HID + i] * l1w[i * 80 + tid];
            s += leaky01(a);
        }
        s80[tid] = s;
    }
    __syncthreads();
    if (tid < 10) {
        float a = l2b[tid];
        for (int f = 0; f < 80; ++f) a += s80[f] * l2w[f * 10 + tid];
        lg[tid] = leaky01(a);
    }
    __syncthreads();
    if (tid == 0) {
        float m = lg[0];
        for (int j = 1; j < 10; ++j) m = fmaxf(m, lg[j]);
        float se = 0.0f;
        for (int j = 0; j < 10; ++j) se += expf(lg[j] - m);
        float ls = logf(se);
        for (int j = 0; j < 10; ++j) out[b * 10 + j] = lg[j] - m - ls;
        if (b == 0) out[640] = klg[0] * (1.0f / 64.0f);
    }
}

extern "C" void kernel_launch(void* const* d_in, const int* in_sizes, int n_in,
                              void* d_out, int out_size, void* d_ws, size_t ws_size,
                              hipStream_t stream) {
    const float* x       = (const float*)d_in[0];
    const int*   ei      = (const int*)d_in[1];
    // d_in[2] = batch (unused: equal-size graphs -> reshape)
    const float* w_embed = (const float*)d_in[3];
    const float* b_embed = (const float*)d_in[4];
    const float* k1      = (const float*)d_in[21];
    const float* conv1_w = (const float*)d_in[22];
    const float* lin1_w  = (const float*)d_in[23];
    const float* lin1_b  = (const float*)d_in[24];
    // d_in[25] k2, d_in[26] conv2_w: analytically dead (K=1 pool -> S2 == 1)
    const float* lin2_w  = (const float*)d_in[27];
    const float* lin2_b  = (const float*)d_in[28];
    float* out = (float*)d_out;

    char* w = (char*)d_ws;
    float* h    = (float*)(w + 0);            // 131072*32*4 = 16,777,216
    float* g    = (float*)(w + 16777216);     // 16,777,216
    float* asv  = (float*)(w + 33554432);     // 524,288
    float* adv  = (float*)(w + 34078720);     // 524,288
    float* S1   = (float*)(w + 34603008);     // 5,242,880
    int*   esrc = (int*)  (w + 39845888);     // 8,388,608
    int*   rp   = (int*)  (w + 48234496);     // 524,544 (131073 ints, padded)
    int*   cur  = (int*)  (w + 48759040);     // 524,288
    int*   bs   = (int*)  (w + 49283328);     // 2,048
    float* xo   = (float*)(w + 49285376);     // 81,920
    float* cs   = (float*)(w + 49367296);     // 2,560
    float* klg  = (float*)(w + 49369856);     // 4

    // zero accumulators (ws is poisoned before every call)
    hipMemsetAsync(cur, 0, N_NODES * sizeof(int), stream);
    hipMemsetAsync(xo, 0, 81920 + 2560 + 4, stream);

    // embed
    k_embed<<<N_NODES / 8, 256, 0, stream>>>(x, w_embed, b_embed, h);

    // CSR by dst (shared by both GAT layers)
    k_count<<<N_EDGES / 256, 256, 0, stream>>>(ei, cur);
    k_scan1<<<N_NODES / 256, 256, 0, stream>>>(cur, rp, bs);
    k_scan2<<<1, 512, 0, stream>>>(bs);
    k_scan3<<<N_NODES / 256, 256, 0, stream>>>(rp, bs, cur);
    k_fill<<<N_EDGES / 256, 256, 0, stream>>>(ei, cur, esrc);

    // two DeepGCN res+ blocks
    for (int l = 0; l < 2; ++l) {
        int o = 5 + l * 8;
        const float* gw  = (const float*)d_in[o + 0];
        const float* asr = (const float*)d_in[o + 1];
        const float* ads = (const float*)d_in[o + 2];
        const float* gbb = (const float*)d_in[o + 3];
        const float* bg  = (const float*)d_in[o + 4];
        const float* bb  = (const float*)d_in[o + 5];
        const float* bm  = (const float*)d_in[o + 6];
        const float* bv  = (const float*)d_in[o + 7];
        k_gat_pre<<<N_NODES / 8, 256, 0, stream>>>(h, gw, asr, ads, bg, bb, bm, bv, g, asv, adv);
        k_aggr<<<N_NODES / 8, 256, 0, stream>>>(h, g, asv, adv, rp, esrc, gbb);
    }

    // mem_pool 1 + kl
    k_mem1<<<N_NODES / 256, 256, 0, stream>>>(h, k1, conv1_w, S1, xo, cs);
    k_kl<<<N_NODES / 256, 256, 0, stream>>>(S1, cs, klg);

    // head (x1 -> leaky -> sum over clusters -> lin2 -> log_softmax; + kl out)
    k_head<<<NB, 128, 0, stream>>>(xo, lin1_w, lin1_b, lin2_w, lin2_b, klg, out);
}

// Round 2
// 616.445 us; speedup vs baseline: 1.3444x; 1.3444x over previous
//
#include <hip/hip_runtime.h>
#include <hip/hip_bf16.h>

#define N_NODES 131072
#define N_EDGES 2097152
#define NB 64
#define N_PER 2048
#define IN_CH 128
#define HID 32
#define NBKT 512            // buckets of 256 nodes each (bucket = dst >> 8)

__device__ __forceinline__ float leaky01(float v) { return v >= 0.0f ? v : 0.01f * v; }
__device__ __forceinline__ float leaky2(float v)  { return v >= 0.0f ? v : 0.2f  * v; }

// ---------------- embed: h = x @ w_embed + b_embed (32 rows / block) ----------------
__global__ void k_embed(const float* __restrict__ x, const float* __restrict__ W,
                        const float* __restrict__ bias, float* __restrict__ h) {
    __shared__ float4 sW4[IN_CH * HID / 4];   // 16 KB
    __shared__ float4 sx4[32 * IN_CH / 4];    // 16 KB
    int tid = threadIdx.x;
    const float4* W4 = (const float4*)W;
    for (int i = tid; i < IN_CH * HID / 4; i += 256) sW4[i] = W4[i];
    const float4* x4 = (const float4*)(x + (size_t)blockIdx.x * 32 * IN_CH);
    for (int i = tid; i < 32 * IN_CH / 4; i += 256) sx4[i] = x4[i];
    __syncthreads();
    const float* sW = (const float*)sW4;
    const float* sx = (const float*)sx4;
    int r0 = tid >> 5, c = tid & 31;
    float b = bias[c];
    float acc0 = b, acc1 = b, acc2 = b, acc3 = b;
    #pragma unroll
    for (int k = 0; k < IN_CH; ++k) {
        float w = sW[k * HID + c];
        acc0 += sx[(r0     ) * IN_CH + k] * w;
        acc1 += sx[(r0 +  8) * IN_CH + k] * w;
        acc2 += sx[(r0 + 16) * IN_CH + k] * w;
        acc3 += sx[(r0 + 24) * IN_CH + k] * w;
    }
    int row = blockIdx.x * 32 + r0;
    h[(row     ) * HID + c] = acc0;
    h[(row +  8) * HID + c] = acc1;
    h[(row + 16) * HID + c] = acc2;
    h[(row + 24) * HID + c] = acc3;
}

// ---------------- CSR build (bucketed counting sort) ----------------
// bucket = dst >> 8 (512 buckets x 256 nodes); pk entry = src | (dst&255)<<17

__global__ void kb_count(const int* __restrict__ ei, int* __restrict__ bcnt) {
    __shared__ int hist[NBKT];
    int tid = threadIdx.x;
    hist[tid] = 0; hist[tid + 256] = 0;
    __syncthreads();
    int e0 = blockIdx.x * 8192;
    #pragma unroll 4
    for (int k = 0; k < 32; ++k) {
        int d = ei[N_EDGES + e0 + k * 256 + tid];
        atomicAdd(&hist[d >> 8], 1);
    }
    __syncthreads();
    atomicAdd(&bcnt[tid], hist[tid]);
    atomicAdd(&bcnt[tid + 256], hist[tid + 256]);
}

__global__ void kb_bscan(const int* __restrict__ bcnt, int* __restrict__ bbase,
                         int* __restrict__ bcur) {
    __shared__ int s[NBKT];
    int tid = threadIdx.x;
    int v = bcnt[tid];
    s[tid] = v; __syncthreads();
    for (int off = 1; off < NBKT; off <<= 1) {
        int t = (tid >= off) ? s[tid - off] : 0;
        __syncthreads();
        s[tid] += t;
        __syncthreads();
    }
    int ex = s[tid] - v;
    bbase[tid] = ex;
    bcur[tid] = ex;
}

__global__ void kb_scatter(const int* __restrict__ ei, int* __restrict__ bcur,
                           unsigned int* __restrict__ pk) {
    __shared__ int hist[NBKT];
    __shared__ int base[NBKT];
    int tid = threadIdx.x;
    hist[tid] = 0; hist[tid + 256] = 0;
    __syncthreads();
    int e0 = blockIdx.x * 8192;
    #pragma unroll 4
    for (int k = 0; k < 32; ++k) {
        int d = ei[N_EDGES + e0 + k * 256 + tid];
        atomicAdd(&hist[d >> 8], 1);
    }
    __syncthreads();
    base[tid] = atomicAdd(&bcur[tid], hist[tid]);
    base[tid + 256] = atomicAdd(&bcur[tid + 256], hist[tid + 256]);
    __syncthreads();
    hist[tid] = 0; hist[tid + 256] = 0;
    __syncthreads();
    for (int k = 0; k < 32; ++k) {
        int e = e0 + k * 256 + tid;
        int d = ei[N_EDGES + e];
        int s = ei[e];
        int b = d >> 8;
        int loc = atomicAdd(&hist[b], 1);
        pk[base[b] + loc] = (unsigned int)s | ((unsigned int)(d & 255) << 17);
    }
}

__global__ void kb_hist(const unsigned int* __restrict__ pk, const int* __restrict__ bcnt,
                        const int* __restrict__ bbase, int* __restrict__ cnt) {
    __shared__ int lc[256];
    int b = blockIdx.x, tid = threadIdx.x;
    lc[tid] = 0; __syncthreads();
    int n = bcnt[b], base = bbase[b];
    for (int i = tid; i < n; i += 256) atomicAdd(&lc[pk[base + i] >> 17], 1);
    __syncthreads();
    cnt[b * 256 + tid] = lc[tid];
}

__global__ void k_scan1(const int* __restrict__ cnt, int* __restrict__ rp, int* __restrict__ bs) {
    __shared__ int s[256];
    int tid = threadIdx.x;
    int gid = blockIdx.x * 256 + tid;
    int v = cnt[gid];
    s[tid] = v; __syncthreads();
    for (int off = 1; off < 256; off <<= 1) {
        int t = (tid >= off) ? s[tid - off] : 0;
        __syncthreads();
        s[tid] += t;
        __syncthreads();
    }
    rp[gid] = s[tid] - v;
    if (tid == 255) bs[blockIdx.x] = s[255];
}

__global__ void k_scan2(int* __restrict__ bs) {
    __shared__ int s[512];
    int tid = threadIdx.x;
    int v = bs[tid];
    s[tid] = v; __syncthreads();
    for (int off = 1; off < 512; off <<= 1) {
        int t = (tid >= off) ? s[tid - off] : 0;
        __syncthreads();
        s[tid] += t;
        __syncthreads();
    }
    bs[tid] = s[tid] - v;
}

__global__ void k_scan3(int* __restrict__ rp, const int* __restrict__ bs) {
    int gid = blockIdx.x * 256 + threadIdx.x;
    rp[gid] += bs[blockIdx.x];
    if (gid == 0) rp[N_NODES] = N_EDGES;
}

__global__ void kb_fill(const unsigned int* __restrict__ pk, const int* __restrict__ bcnt,
                        const int* __restrict__ bbase, const int* __restrict__ rp,
                        int* __restrict__ esrc) {
    __shared__ int lcur[256];
    int b = blockIdx.x, tid = threadIdx.x;
    lcur[tid] = rp[b * 256 + tid];
    __syncthreads();
    int n = bcnt[b], base = bbase[b];
    for (int i = tid; i < n; i += 256) {
        unsigned int v = pk[base + i];
        int pos = atomicAdd(&lcur[v >> 17], 1);
        esrc[pos] = (int)(v & 0x1FFFFu);
    }
}

// ------- GAT pre: t = leaky(BN(h)); g = t@W; as = g@a_src; ad = g@a_dst -------
__global__ void k_gat_pre(const float* __restrict__ h, const float* __restrict__ W,
                          const float* __restrict__ a_src, const float* __restrict__ a_dst,
                          const float* __restrict__ bn_g, const float* __restrict__ bn_b,
                          const float* __restrict__ bn_m, const float* __restrict__ bn_v,
                          float* __restrict__ g, float* __restrict__ asv, float* __restrict__ adv) {
    __shared__ float sW[HID * HID];
    __shared__ float st[8 * HID];
    __shared__ float ssc[HID], ssh[HID];
    int tid = threadIdx.x;
    if (tid < HID) {
        float sc = bn_g[tid] * rsqrtf(bn_v[tid] + 1e-5f);
        ssc[tid] = sc;
        ssh[tid] = bn_b[tid] - bn_m[tid] * sc;
    }
    for (int i = tid; i < HID * HID; i += 256) sW[i] = W[i];
    __syncthreads();
    int base = blockIdx.x * 8 * HID;
    {
        int c = tid & 31;
        float v = h[base + tid];
        v = v * ssc[c] + ssh[c];
        st[tid] = leaky01(v);
    }
    __syncthreads();
    int r = tid >> 5, c = tid & 31;
    float acc = 0.0f;
    #pragma unroll
    for (int k = 0; k < HID; ++k) acc += st[r * HID + k] * sW[k * HID + c];
    g[base + tid] = acc;
    float p = acc * a_src[c];
    #pragma unroll
    for (int m = 16; m >= 1; m >>= 1) p += __shfl_xor(p, m);
    float q = acc * a_dst[c];
    #pragma unroll
    for (int m = 16; m >= 1; m >>= 1) q += __shfl_xor(q, m);
    if (c == 0) {
        int row = blockIdx.x * 8 + r;
        asv[row] = p;
        adv[row] = q;
    }
}

// ------- GAT aggregate: online segment softmax + weighted sum, residual -------
__global__ void k_aggr(float* __restrict__ h, const float* __restrict__ g,
                       const float* __restrict__ asv, const float* __restrict__ adv,
                       const int* __restrict__ rp, const int* __restrict__ esrc,
                       const float* __restrict__ gb) {
    int node = blockIdx.x * 8 + (threadIdx.x >> 5);
    int c = threadIdx.x & 31;
    float ad_i = adv[node];
    float m = leaky2(asv[node] + ad_i);   // self-loop seeds the running state
    float z = 1.0f;
    float acc = g[node * HID + c];
    int beg = rp[node], end = rp[node + 1];
    for (int j = beg; j < end; ++j) {
        int s = esrc[j];
        float lg = leaky2(asv[s] + ad_i);
        float gs = g[s * HID + c];
        if (lg > m) {
            float sc = __expf(m - lg);
            z = z * sc + 1.0f;
            acc = acc * sc + gs;
            m = lg;
        } else {
            float e = __expf(lg - m);
            z += e;
            acc += e * gs;
        }
    }
    h[node * HID + c] += acc / (z + 1e-16f) + gb[c];
}

// ------- mem_pool 1: S1 [N,10], colsum [B,10], xo partial [B,10,32] -------
__global__ void k_mem1(const float* __restrict__ h, const float* __restrict__ k1,
                       const float* __restrict__ conv_w,
                       float* __restrict__ S1, float* __restrict__ xo,
                       float* __restrict__ colsum) {
    __shared__ float sk1[5 * 10 * HID];
    __shared__ float sk2[50];
    __shared__ float scw[5];
    __shared__ float s1l[256][10];
    int tid = threadIdx.x;
    for (int i = tid; i < 5 * 10 * HID; i += 256) sk1[i] = k1[i];
    if (tid < 5) scw[tid] = conv_w[tid];
    __syncthreads();
    if (tid < 50) {
        float s = 0.0f;
        for (int f = 0; f < HID; ++f) { float t = sk1[tid * HID + f]; s += t * t; }
        sk2[tid] = s;
    }
    __syncthreads();

    int nid = blockIdx.x * 256 + tid;
    float xr[HID];
    const float4* xp = (const float4*)(h + nid * HID);
    #pragma unroll
    for (int i = 0; i < 8; ++i) {
        float4 v = xp[i];
        xr[4 * i] = v.x; xr[4 * i + 1] = v.y; xr[4 * i + 2] = v.z; xr[4 * i + 3] = v.w;
    }
    float x2n = 0.0f;
    #pragma unroll
    for (int f = 0; f < HID; ++f) x2n += xr[f] * xr[f];

    float Sc[10];
    #pragma unroll
    for (int k = 0; k < 10; ++k) Sc[k] = 0.0f;

    for (int hh = 0; hh < 5; ++hh) {
        float tmp[10];
        float rsum = 0.0f;
        #pragma unroll
        for (int k = 0; k < 10; ++k) {
            float dot = 0.0f;
            #pragma unroll
            for (int f = 0; f < HID; ++f) dot += xr[f] * sk1[(hh * 10 + k) * HID + f];
            float d = x2n + sk2[hh * 10 + k] - 2.0f * dot;
            d = d > 0.0f ? d : 0.0f;
            float s = 1.0f / (1.0f + d);
            tmp[k] = s;
            rsum += s;
        }
        float w = scw[hh] / rsum;
        #pragma unroll
        for (int k = 0; k < 10; ++k) Sc[k] += tmp[k] * w;
    }
    float mx = Sc[0];
    #pragma unroll
    for (int k = 1; k < 10; ++k) mx = fmaxf(mx, Sc[k]);
    float se = 0.0f;
    #pragma unroll
    for (int k = 0; k < 10; ++k) { float e = __expf(Sc[k] - mx); Sc[k] = e; se += e; }
    float inv = 1.0f / se;
    #pragma unroll
    for (int k = 0; k < 10; ++k) {
        float v = Sc[k] * inv;
        s1l[tid][k] = v;
        S1[nid * 10 + k] = v;
    }
    __syncthreads();

    int b = nid >> 11;
    for (int idx = tid; idx < 320; idx += 256) {
        int k = idx >> 5, f = idx & 31;
        float s = 0.0f;
        const float* xb = h + (blockIdx.x * 256) * HID + f;
        for (int n = 0; n < 256; ++n) s += s1l[n][k] * xb[n * HID];
        atomicAdd(&xo[(b * 10 + k) * HID + f], s);
    }
    for (int k = tid; k < 10; k += 256) {
        float s = 0.0f;
        for (int n = 0; n < 256; ++n) s += s1l[n][k];
        atomicAdd(&colsum[b * 10 + k], s);
    }
}

// ------- kl_loss(S1) accumulation -------
__global__ void k_kl(const float* __restrict__ S1, const float* __restrict__ colsum,
                     float* __restrict__ klg) {
    __shared__ float red[256];
    int tid = threadIdx.x;
    int nid = blockIdx.x * 256 + tid;
    int b = nid >> 11;
    const float* srow = S1 + nid * 10;
    float p[10], sv[10];
    float dsum = 0.0f;
    #pragma unroll
    for (int k = 0; k < 10; ++k) {
        float s = srow[k];
        sv[k] = s;
        float pk = s * s / fmaxf(colsum[b * 10 + k], 1e-15f);
        p[k] = pk;
        dsum += pk;
    }
    float invd = 1.0f / dsum;
    float term = 0.0f;
    #pragma unroll
    for (int k = 0; k < 10; ++k) {
        float pk = fmaxf(p[k] * invd, 1e-15f);
        float s = fmaxf(sv[k], 1e-15f);
        term += pk * (logf(pk) - logf(s));
    }
    red[tid] = term; __syncthreads();
    for (int off = 128; off > 0; off >>= 1) {
        if (tid < off) red[tid] += red[tid + off];
        __syncthreads();
    }
    if (tid == 0) atomicAdd(klg, red[0]);
}

// ------- head: x1 = xo@lin1 + b; mem_pool2 collapses (S2 == ones, kl2 == 0) -------
__global__ void k_head(const float* __restrict__ xo, const float* __restrict__ l1w,
                       const float* __restrict__ l1b, const float* __restrict__ l2w,
                       const float* __restrict__ l2b, const float* __restrict__ klg,
                       float* __restrict__ out) {
    __shared__ float sxo[320];
    __shared__ float s80[80];
    __shared__ float lg[10];
    int b = blockIdx.x, tid = threadIdx.x;
    for (int i = tid; i < 320; i += 128) sxo[i] = xo[b * 320 + i];
    __syncthreads();
    if (tid < 80) {
        float s = 0.0f;
        for (int k = 0; k < 10; ++k) {
            float a = l1b[tid];
            #pragma unroll
            for (int i = 0; i < HID; ++i) a += sxo[k * HID + i] * l1w[i * 80 + tid];
            s += leaky01(a);
        }
        s80[tid] = s;
    }
    __syncthreads();
    if (tid < 10) {
        float a = l2b[tid];
        for (int f = 0; f < 80; ++f) a += s80[f] * l2w[f * 10 + tid];
        lg[tid] = leaky01(a);
    }
    __syncthreads();
    if (tid == 0) {
        float m = lg[0];
        for (int j = 1; j < 10; ++j) m = fmaxf(m, lg[j]);
        float se = 0.0f;
        for (int j = 0; j < 10; ++j) se += expf(lg[j] - m);
        float ls = logf(se);
        for (int j = 0; j < 10; ++j) out[b * 10 + j] = lg[j] - m - ls;
        if (b == 0) out[640] = klg[0] * (1.0f / 64.0f);
    }
}

extern "C" void kernel_launch(void* const* d_in, const int* in_sizes, int n_in,
                              void* d_out, int out_size, void* d_ws, size_t ws_size,
                              hipStream_t stream) {
    const float* x       = (const float*)d_in[0];
    const int*   ei      = (const int*)d_in[1];
    const float* w_embed = (const float*)d_in[3];
    const float* b_embed = (const float*)d_in[4];
    const float* k1      = (const float*)d_in[21];
    const float* conv1_w = (const float*)d_in[22];
    const float* lin1_w  = (const float*)d_in[23];
    const float* lin1_b  = (const float*)d_in[24];
    const float* lin2_w  = (const float*)d_in[27];
    const float* lin2_b  = (const float*)d_in[28];
    float* out = (float*)d_out;

    char* w = (char*)d_ws;
    float* h    = (float*)(w + 0);            // 16,777,216
    float* g    = (float*)(w + 16777216);     // 16,777,216 (pk overlays: CSR-build only)
    unsigned int* pk = (unsigned int*)(w + 16777216);   // 8,388,608 (dead before g written)
    float* asv  = (float*)(w + 33554432);     // 524,288
    float* adv  = (float*)(w + 34078720);     // 524,288
    float* S1   = (float*)(w + 34603008);     // 5,242,880
    int*   esrc = (int*)  (w + 39845888);     // 8,388,608
    int*   rp   = (int*)  (w + 48234496);     // 524,544
    int*   cnt  = (int*)  (w + 48759040);     // 524,288
    int*   bs   = (int*)  (w + 49283328);     // 2,048
    int*   bcnt = (int*)  (w + 49285376);     // 2,048
    int*   bbase= (int*)  (w + 49287424);     // 2,048
    int*   bcur = (int*)  (w + 49289472);     // 2,048
    float* xo   = (float*)(w + 49291520);     // 81,920
    float* cs   = (float*)(w + 49373440);     // 2,560
    float* klg  = (float*)(w + 49376000);     // 4

    hipMemsetAsync(bcnt, 0, NBKT * sizeof(int), stream);
    hipMemsetAsync(xo, 0, 81920 + 2560 + 4, stream);

    // embed (runs while CSR build proceeds on same stream)
    k_embed<<<N_NODES / 32, 256, 0, stream>>>(x, w_embed, b_embed, h);

    // CSR by dst via 512-bucket counting sort (shared by both GAT layers)
    kb_count<<<N_EDGES / 8192, 256, 0, stream>>>(ei, bcnt);
    kb_bscan<<<1, NBKT, 0, stream>>>(bcnt, bbase, bcur);
    kb_scatter<<<N_EDGES / 8192, 256, 0, stream>>>(ei, bcur, pk);
    kb_hist<<<NBKT, 256, 0, stream>>>(pk, bcnt, bbase, cnt);
    k_scan1<<<N_NODES / 256, 256, 0, stream>>>(cnt, rp, bs);
    k_scan2<<<1, 512, 0, stream>>>(bs);
    k_scan3<<<N_NODES / 256, 256, 0, stream>>>(rp, bs);
    kb_fill<<<NBKT, 256, 0, stream>>>(pk, bcnt, bbase, rp, esrc);

    // two DeepGCN res+ blocks
    for (int l = 0; l < 2; ++l) {
        int o = 5 + l * 8;
        const float* gw  = (const float*)d_in[o + 0];
        const float* asr = (const float*)d_in[o + 1];
        const float* ads = (const float*)d_in[o + 2];
        const float* gbb = (const float*)d_in[o + 3];
        const float* bg  = (const float*)d_in[o + 4];
        const float* bb  = (const float*)d_in[o + 5];
        const float* bm  = (const float*)d_in[o + 6];
        const float* bv  = (const float*)d_in[o + 7];
        k_gat_pre<<<N_NODES / 8, 256, 0, stream>>>(h, gw, asr, ads, bg, bb, bm, bv, g, asv, adv);
        k_aggr<<<N_NODES / 8, 256, 0, stream>>>(h, g, asv, adv, rp, esrc, gbb);
    }

    // mem_pool 1 + kl
    k_mem1<<<N_NODES / 256, 256, 0, stream>>>(h, k1, conv1_w, S1, xo, cs);
    k_kl<<<N_NODES / 256, 256, 0, stream>>>(S1, cs, klg);

    // head
    k_head<<<NB, 128, 0, stream>>>(xo, lin1_w, lin1_b, lin2_w, lin2_b, klg, out);
}

// Round 3
// 488.448 us; speedup vs baseline: 1.6967x; 1.2620x over previous
//
#include <hip/hip_runtime.h>
#include <hip/hip_bf16.h>

#define N_NODES 131072
#define N_EDGES 2097152
#define NB 64
#define N_PER 2048
#define IN_CH 128
#define HID 32
#define NBKT 512            // buckets of 256 nodes each (bucket = dst >> 8)

__device__ __forceinline__ float leaky01(float v) { return v >= 0.0f ? v : 0.01f * v; }
__device__ __forceinline__ float leaky2(float v)  { return v >= 0.0f ? v : 0.2f  * v; }

// ---------------- embed: h = x @ w_embed + b_embed (32 rows / block) ----------------
__global__ void k_embed(const float* __restrict__ x, const float* __restrict__ W,
                        const float* __restrict__ bias, float* __restrict__ h) {
    __shared__ float4 sW4[IN_CH * HID / 4];   // 16 KB
    __shared__ float4 sx4[32 * IN_CH / 4];    // 16 KB
    int tid = threadIdx.x;
    const float4* W4 = (const float4*)W;
    for (int i = tid; i < IN_CH * HID / 4; i += 256) sW4[i] = W4[i];
    const float4* x4 = (const float4*)(x + (size_t)blockIdx.x * 32 * IN_CH);
    for (int i = tid; i < 32 * IN_CH / 4; i += 256) sx4[i] = x4[i];
    __syncthreads();
    const float* sW = (const float*)sW4;
    const float* sx = (const float*)sx4;
    int r0 = tid >> 5, c = tid & 31;
    float b = bias[c];
    float acc0 = b, acc1 = b, acc2 = b, acc3 = b;
    #pragma unroll
    for (int k = 0; k < IN_CH; ++k) {
        float w = sW[k * HID + c];
        acc0 += sx[(r0     ) * IN_CH + k] * w;
        acc1 += sx[(r0 +  8) * IN_CH + k] * w;
        acc2 += sx[(r0 + 16) * IN_CH + k] * w;
        acc3 += sx[(r0 + 24) * IN_CH + k] * w;
    }
    int row = blockIdx.x * 32 + r0;
    h[(row     ) * HID + c] = acc0;
    h[(row +  8) * HID + c] = acc1;
    h[(row + 16) * HID + c] = acc2;
    h[(row + 24) * HID + c] = acc3;
}

// ---------------- CSR build (bucketed counting sort) ----------------
// bucket = dst >> 8 (512 buckets x 256 nodes); pk entry = src | (dst&255)<<17

__global__ void kb_count(const int* __restrict__ ei, int* __restrict__ bcnt) {
    __shared__ int hist[NBKT];
    int tid = threadIdx.x;
    hist[tid] = 0; hist[tid + 256] = 0;
    __syncthreads();
    int e0 = blockIdx.x * 8192;
    #pragma unroll 4
    for (int k = 0; k < 32; ++k) {
        int d = ei[N_EDGES + e0 + k * 256 + tid];
        atomicAdd(&hist[d >> 8], 1);
    }
    __syncthreads();
    atomicAdd(&bcnt[tid], hist[tid]);
    atomicAdd(&bcnt[tid + 256], hist[tid + 256]);
}

__global__ void kb_bscan(const int* __restrict__ bcnt, int* __restrict__ bbase,
                         int* __restrict__ bcur) {
    __shared__ int s[NBKT];
    int tid = threadIdx.x;
    int v = bcnt[tid];
    s[tid] = v; __syncthreads();
    for (int off = 1; off < NBKT; off <<= 1) {
        int t = (tid >= off) ? s[tid - off] : 0;
        __syncthreads();
        s[tid] += t;
        __syncthreads();
    }
    int ex = s[tid] - v;
    bbase[tid] = ex;
    bcur[tid] = ex;
}

__global__ void kb_scatter(const int* __restrict__ ei, int* __restrict__ bcur,
                           unsigned int* __restrict__ pk) {
    __shared__ int hist[NBKT];
    __shared__ int base[NBKT];
    int tid = threadIdx.x;
    hist[tid] = 0; hist[tid + 256] = 0;
    __syncthreads();
    int e0 = blockIdx.x * 8192;
    #pragma unroll 4
    for (int k = 0; k < 32; ++k) {
        int d = ei[N_EDGES + e0 + k * 256 + tid];
        atomicAdd(&hist[d >> 8], 1);
    }
    __syncthreads();
    base[tid] = atomicAdd(&bcur[tid], hist[tid]);
    base[tid + 256] = atomicAdd(&bcur[tid + 256], hist[tid + 256]);
    __syncthreads();
    hist[tid] = 0; hist[tid + 256] = 0;
    __syncthreads();
    for (int k = 0; k < 32; ++k) {
        int e = e0 + k * 256 + tid;
        int d = ei[N_EDGES + e];
        int s = ei[e];
        int b = d >> 8;
        int loc = atomicAdd(&hist[b], 1);
        pk[base[b] + loc] = (unsigned int)s | ((unsigned int)(d & 255) << 17);
    }
}

__global__ void kb_hist(const unsigned int* __restrict__ pk, const int* __restrict__ bcnt,
                        const int* __restrict__ bbase, int* __restrict__ cnt) {
    __shared__ int lc[256];
    int b = blockIdx.x, tid = threadIdx.x;
    lc[tid] = 0; __syncthreads();
    int n = bcnt[b], base = bbase[b];
    for (int i = tid; i < n; i += 256) atomicAdd(&lc[pk[base + i] >> 17], 1);
    __syncthreads();
    cnt[b * 256 + tid] = lc[tid];
}

__global__ void k_scan1(const int* __restrict__ cnt, int* __restrict__ rp, int* __restrict__ bs) {
    __shared__ int s[256];
    int tid = threadIdx.x;
    int gid = blockIdx.x * 256 + tid;
    int v = cnt[gid];
    s[tid] = v; __syncthreads();
    for (int off = 1; off < 256; off <<= 1) {
        int t = (tid >= off) ? s[tid - off] : 0;
        __syncthreads();
        s[tid] += t;
        __syncthreads();
    }
    rp[gid] = s[tid] - v;
    if (tid == 255) bs[blockIdx.x] = s[255];
}

__global__ void k_scan2(int* __restrict__ bs) {
    __shared__ int s[512];
    int tid = threadIdx.x;
    int v = bs[tid];
    s[tid] = v; __syncthreads();
    for (int off = 1; off < 512; off <<= 1) {
        int t = (tid >= off) ? s[tid - off] : 0;
        __syncthreads();
        s[tid] += t;
        __syncthreads();
    }
    bs[tid] = s[tid] - v;
}

__global__ void k_scan3(int* __restrict__ rp, const int* __restrict__ bs) {
    int gid = blockIdx.x * 256 + threadIdx.x;
    rp[gid] += bs[blockIdx.x];
    if (gid == 0) rp[N_NODES] = N_EDGES;
}

__global__ void kb_fill(const unsigned int* __restrict__ pk, const int* __restrict__ bcnt,
                        const int* __restrict__ bbase, const int* __restrict__ rp,
                        int* __restrict__ esrc) {
    __shared__ int lcur[256];
    int b = blockIdx.x, tid = threadIdx.x;
    lcur[tid] = rp[b * 256 + tid];
    __syncthreads();
    int n = bcnt[b], base = bbase[b];
    for (int i = tid; i < n; i += 256) {
        unsigned int v = pk[base + i];
        int pos = atomicAdd(&lcur[v >> 17], 1);
        esrc[pos] = (int)(v & 0x1FFFFu);
    }
}

// ------- GAT pre: t = leaky(BN(h)); g = t@W; as = g@a_src; ad = g@a_dst -------
// 32 rows per block
__global__ void k_gat_pre(const float* __restrict__ h, const float* __restrict__ W,
                          const float* __restrict__ a_src, const float* __restrict__ a_dst,
                          const float* __restrict__ bn_g, const float* __restrict__ bn_b,
                          const float* __restrict__ bn_m, const float* __restrict__ bn_v,
                          float* __restrict__ g, float* __restrict__ asv, float* __restrict__ adv) {
    __shared__ float sW[HID * HID];
    __shared__ float st[32 * HID];
    __shared__ float ssc[HID], ssh[HID];
    int tid = threadIdx.x;
    if (tid < HID) {
        float sc = bn_g[tid] * rsqrtf(bn_v[tid] + 1e-5f);
        ssc[tid] = sc;
        ssh[tid] = bn_b[tid] - bn_m[tid] * sc;
    }
    for (int i = tid; i < HID * HID; i += 256) sW[i] = W[i];
    __syncthreads();
    int base = blockIdx.x * 32 * HID;
    for (int i = tid; i < 32 * HID; i += 256) {
        int ch = i & 31;
        st[i] = leaky01(h[base + i] * ssc[ch] + ssh[ch]);
    }
    __syncthreads();
    int r0 = tid >> 5, c = tid & 31;
    float as_c = a_src[c], ad_c = a_dst[c];
    float acc0 = 0.f, acc1 = 0.f, acc2 = 0.f, acc3 = 0.f;
    #pragma unroll
    for (int k = 0; k < HID; ++k) {
        float w = sW[k * HID + c];
        acc0 += st[(r0     ) * HID + k] * w;
        acc1 += st[(r0 +  8) * HID + k] * w;
        acc2 += st[(r0 + 16) * HID + k] * w;
        acc3 += st[(r0 + 24) * HID + k] * w;
    }
    g[base + (r0     ) * HID + c] = acc0;
    g[base + (r0 +  8) * HID + c] = acc1;
    g[base + (r0 + 16) * HID + c] = acc2;
    g[base + (r0 + 24) * HID + c] = acc3;
    float p0 = acc0 * as_c, p1 = acc1 * as_c, p2 = acc2 * as_c, p3 = acc3 * as_c;
    float q0 = acc0 * ad_c, q1 = acc1 * ad_c, q2 = acc2 * ad_c, q3 = acc3 * ad_c;
    #pragma unroll
    for (int m = 16; m >= 1; m >>= 1) {
        p0 += __shfl_xor(p0, m); p1 += __shfl_xor(p1, m);
        p2 += __shfl_xor(p2, m); p3 += __shfl_xor(p3, m);
        q0 += __shfl_xor(q0, m); q1 += __shfl_xor(q1, m);
        q2 += __shfl_xor(q2, m); q3 += __shfl_xor(q3, m);
    }
    if (c == 0) {
        int row = blockIdx.x * 32 + r0;
        asv[row     ] = p0;  adv[row     ] = q0;
        asv[row +  8] = p1;  adv[row +  8] = q1;
        asv[row + 16] = p2;  adv[row + 16] = q2;
        asv[row + 24] = p3;  adv[row + 24] = q3;
    }
}

// ------- per-node max of asv over in-neighborhood (incl self) -------
// leaky2 is monotone, so max logit = leaky2(smax + adv[node]) can be formed later.
__global__ void k_maxl(const float* __restrict__ asv, const int* __restrict__ rp,
                       const int* __restrict__ esrc, float* __restrict__ smax) {
    int node = blockIdx.x * 256 + threadIdx.x;
    float m = asv[node];                      // self-loop
    int beg = rp[node], end = rp[node + 1];
    int j = beg;
    for (; j + 4 <= end; j += 4) {
        int s0 = esrc[j], s1 = esrc[j + 1], s2 = esrc[j + 2], s3 = esrc[j + 3];
        float a0 = asv[s0], a1 = asv[s1], a2 = asv[s2], a3 = asv[s3];
        m = fmaxf(m, fmaxf(fmaxf(a0, a1), fmaxf(a2, a3)));
    }
    for (; j < end; ++j) m = fmaxf(m, asv[esrc[j]]);
    smax[node] = m;
}

// ------- GAT aggregate: fixed-max softmax, independent FMA iterations -------
__global__ void k_aggr(float* __restrict__ h, const float* __restrict__ g,
                       const float* __restrict__ asv, const float* __restrict__ adv,
                       const float* __restrict__ smax,
                       const int* __restrict__ rp, const int* __restrict__ esrc,
                       const float* __restrict__ gb) {
    int node = blockIdx.x * 8 + (threadIdx.x >> 5);
    int c = threadIdx.x & 31;
    float gbc = gb[c];
    float ad_i = adv[node];
    float m = leaky2(smax[node] + ad_i);
    float e_self = __expf(leaky2(asv[node] + ad_i) - m);
    float z = e_self;
    float acc = e_self * g[node * HID + c];
    int beg = rp[node], end = rp[node + 1];
    int j = beg;
    for (; j + 4 <= end; j += 4) {
        int s0 = esrc[j], s1 = esrc[j + 1], s2 = esrc[j + 2], s3 = esrc[j + 3];
        float l0 = asv[s0], l1 = asv[s1], l2 = asv[s2], l3 = asv[s3];
        float g0 = g[s0 * HID + c], g1 = g[s1 * HID + c];
        float g2 = g[s2 * HID + c], g3 = g[s3 * HID + c];
        float e0 = __expf(leaky2(l0 + ad_i) - m);
        float e1 = __expf(leaky2(l1 + ad_i) - m);
        float e2 = __expf(leaky2(l2 + ad_i) - m);
        float e3 = __expf(leaky2(l3 + ad_i) - m);
        z += (e0 + e1) + (e2 + e3);
        acc += e0 * g0 + e1 * g1 + e2 * g2 + e3 * g3;
    }
    for (; j < end; ++j) {
        int s = esrc[j];
        float e = __expf(leaky2(asv[s] + ad_i) - m);
        z += e;
        acc += e * g[s * HID + c];
    }
    h[node * HID + c] += acc / (z + 1e-16f) + gbc;
}

// ------- mem_pool 1: S1 [N,10], colsum [B,10], xo partial [B,10,32] -------
__global__ void k_mem1(const float* __restrict__ h, const float* __restrict__ k1,
                       const float* __restrict__ conv_w,
                       float* __restrict__ S1, float* __restrict__ xo,
                       float* __restrict__ colsum) {
    __shared__ float sk1[5 * 10 * HID];
    __shared__ float sk2[50];
    __shared__ float scw[5];
    __shared__ float s1l[256][10];
    int tid = threadIdx.x;
    for (int i = tid; i < 5 * 10 * HID; i += 256) sk1[i] = k1[i];
    if (tid < 5) scw[tid] = conv_w[tid];
    __syncthreads();
    if (tid < 50) {
        float s = 0.0f;
        for (int f = 0; f < HID; ++f) { float t = sk1[tid * HID + f]; s += t * t; }
        sk2[tid] = s;
    }
    __syncthreads();

    int nid = blockIdx.x * 256 + tid;
    float xr[HID];
    const float4* xp = (const float4*)(h + nid * HID);
    #pragma unroll
    for (int i = 0; i < 8; ++i) {
        float4 v = xp[i];
        xr[4 * i] = v.x; xr[4 * i + 1] = v.y; xr[4 * i + 2] = v.z; xr[4 * i + 3] = v.w;
    }
    float x2n = 0.0f;
    #pragma unroll
    for (int f = 0; f < HID; ++f) x2n += xr[f] * xr[f];

    float Sc[10];
    #pragma unroll
    for (int k = 0; k < 10; ++k) Sc[k] = 0.0f;

    for (int hh = 0; hh < 5; ++hh) {
        float tmp[10];
        float rsum = 0.0f;
        #pragma unroll
        for (int k = 0; k < 10; ++k) {
            float dot = 0.0f;
            #pragma unroll
            for (int f = 0; f < HID; ++f) dot += xr[f] * sk1[(hh * 10 + k) * HID + f];
            float d = x2n + sk2[hh * 10 + k] - 2.0f * dot;
            d = d > 0.0f ? d : 0.0f;
            float s = 1.0f / (1.0f + d);
            tmp[k] = s;
            rsum += s;
        }
        float w = scw[hh] / rsum;
        #pragma unroll
        for (int k = 0; k < 10; ++k) Sc[k] += tmp[k] * w;
    }
    float mx = Sc[0];
    #pragma unroll
    for (int k = 1; k < 10; ++k) mx = fmaxf(mx, Sc[k]);
    float se = 0.0f;
    #pragma unroll
    for (int k = 0; k < 10; ++k) { float e = __expf(Sc[k] - mx); Sc[k] = e; se += e; }
    float inv = 1.0f / se;
    #pragma unroll
    for (int k = 0; k < 10; ++k) {
        float v = Sc[k] * inv;
        s1l[tid][k] = v;
        S1[nid * 10 + k] = v;
    }
    __syncthreads();

    int b = nid >> 11;
    for (int idx = tid; idx < 320; idx += 256) {
        int k = idx >> 5, f = idx & 31;
        float s = 0.0f;
        const float* xb = h + (blockIdx.x * 256) * HID + f;
        for (int n = 0; n < 256; ++n) s += s1l[n][k] * xb[n * HID];
        atomicAdd(&xo[(b * 10 + k) * HID + f], s);
    }
    for (int k = tid; k < 10; k += 256) {
        float s = 0.0f;
        for (int n = 0; n < 256; ++n) s += s1l[n][k];
        atomicAdd(&colsum[b * 10 + k], s);
    }
}

// ------- kl_loss(S1) accumulation -------
__global__ void k_kl(const float* __restrict__ S1, const float* __restrict__ colsum,
                     float* __restrict__ klg) {
    __shared__ float red[256];
    int tid = threadIdx.x;
    int nid = blockIdx.x * 256 + tid;
    int b = nid >> 11;
    const float* srow = S1 + nid * 10;
    float p[10], sv[10];
    float dsum = 0.0f;
    #pragma unroll
    for (int k = 0; k < 10; ++k) {
        float s = srow[k];
        sv[k] = s;
        float pk = s * s / fmaxf(colsum[b * 10 + k], 1e-15f);
        p[k] = pk;
        dsum += pk;
    }
    float invd = 1.0f / dsum;
    float term = 0.0f;
    #pragma unroll
    for (int k = 0; k < 10; ++k) {
        float pk = fmaxf(p[k] * invd, 1e-15f);
        float s = fmaxf(sv[k], 1e-15f);
        term += pk * (logf(pk) - logf(s));
    }
    red[tid] = term; __syncthreads();
    for (int off = 128; off > 0; off >>= 1) {
        if (tid < off) red[tid] += red[tid + off];
        __syncthreads();
    }
    if (tid == 0) atomicAdd(klg, red[0]);
}

// ------- head: x1 = xo@lin1 + b; mem_pool2 collapses (S2 == ones, kl2 == 0) -------
__global__ void k_head(const float* __restrict__ xo, const float* __restrict__ l1w,
                       const float* __restrict__ l1b, const float* __restrict__ l2w,
                       const float* __restrict__ l2b, const float* __restrict__ klg,
                       float* __restrict__ out) {
    __shared__ float sxo[320];
    __shared__ float s80[80];
    __shared__ float lg[10];
    int b = blockIdx.x, tid = threadIdx.x;
    for (int i = tid; i < 320; i += 128) sxo[i] = xo[b * 320 + i];
    __syncthreads();
    if (tid < 80) {
        float s = 0.0f;
        for (int k = 0; k < 10; ++k) {
            float a = l1b[tid];
            #pragma unroll
            for (int i = 0; i < HID; ++i) a += sxo[k * HID + i] * l1w[i * 80 + tid];
            s += leaky01(a);
        }
        s80[tid] = s;
    }
    __syncthreads();
    if (tid < 10) {
        float a = l2b[tid];
        for (int f = 0; f < 80; ++f) a += s80[f] * l2w[f * 10 + tid];
        lg[tid] = leaky01(a);
    }
    __syncthreads();
    if (tid == 0) {
        float m = lg[0];
        for (int j = 1; j < 10; ++j) m = fmaxf(m, lg[j]);
        float se = 0.0f;
        for (int j = 0; j < 10; ++j) se += expf(lg[j] - m);
        float ls = logf(se);
        for (int j = 0; j < 10; ++j) out[b * 10 + j] = lg[j] - m - ls;
        if (b == 0) out[640] = klg[0] * (1.0f / 64.0f);
    }
}

extern "C" void kernel_launch(void* const* d_in, const int* in_sizes, int n_in,
                              void* d_out, int out_size, void* d_ws, size_t ws_size,
                              hipStream_t stream) {
    const float* x       = (const float*)d_in[0];
    const int*   ei      = (const int*)d_in[1];
    const float* w_embed = (const float*)d_in[3];
    const float* b_embed = (const float*)d_in[4];
    const float* k1      = (const float*)d_in[21];
    const float* conv1_w = (const float*)d_in[22];
    const float* lin1_w  = (const float*)d_in[23];
    const float* lin1_b  = (const float*)d_in[24];
    const float* lin2_w  = (const float*)d_in[27];
    const float* lin2_b  = (const float*)d_in[28];
    float* out = (float*)d_out;

    char* w = (char*)d_ws;
    float* h    = (float*)(w + 0);            // 16,777,216
    float* g    = (float*)(w + 16777216);     // 16,777,216 (pk overlays: CSR-build only)
    unsigned int* pk = (unsigned int*)(w + 16777216);   // 8,388,608 (dead before g written)
    float* asv  = (float*)(w + 33554432);     // 524,288
    float* adv  = (float*)(w + 34078720);     // 524,288
    float* S1   = (float*)(w + 34603008);     // 5,242,880
    int*   esrc = (int*)  (w + 39845888);     // 8,388,608
    int*   rp   = (int*)  (w + 48234496);     // 524,544
    int*   cnt  = (int*)  (w + 48759040);     // 524,288 (dead after scan1 -> reused as smax)
    float* smax = (float*)cnt;
    int*   bs   = (int*)  (w + 49283328);     // 2,048
    int*   bcnt = (int*)  (w + 49285376);     // 2,048
    int*   bbase= (int*)  (w + 49287424);     // 2,048
    int*   bcur = (int*)  (w + 49289472);     // 2,048
    float* xo   = (float*)(w + 49291520);     // 81,920
    float* cs   = (float*)(w + 49373440);     // 2,560
    float* klg  = (float*)(w + 49376000);     // 4

    hipMemsetAsync(bcnt, 0, NBKT * sizeof(int), stream);
    hipMemsetAsync(xo, 0, 81920 + 2560 + 4, stream);

    // embed
    k_embed<<<N_NODES / 32, 256, 0, stream>>>(x, w_embed, b_embed, h);

    // CSR by dst via 512-bucket counting sort (shared by both GAT layers)
    kb_count<<<N_EDGES / 8192, 256, 0, stream>>>(ei, bcnt);
    kb_bscan<<<1, NBKT, 0, stream>>>(bcnt, bbase, bcur);
    kb_scatter<<<N_EDGES / 8192, 256, 0, stream>>>(ei, bcur, pk);
    kb_hist<<<NBKT, 256, 0, stream>>>(pk, bcnt, bbase, cnt);
    k_scan1<<<N_NODES / 256, 256, 0, stream>>>(cnt, rp, bs);
    k_scan2<<<1, 512, 0, stream>>>(bs);
    k_scan3<<<N_NODES / 256, 256, 0, stream>>>(rp, bs);
    kb_fill<<<NBKT, 256, 0, stream>>>(pk, bcnt, bbase, rp, esrc);

    // two DeepGCN res+ blocks
    for (int l = 0; l < 2; ++l) {
        int o = 5 + l * 8;
        const float* gw  = (const float*)d_in[o + 0];
        const float* asr = (const float*)d_in[o + 1];
        const float* ads = (const float*)d_in[o + 2];
        const float* gbb = (const float*)d_in[o + 3];
        const float* bg  = (const float*)d_in[o + 4];
        const float* bb  = (const float*)d_in[o + 5];
        const float* bm  = (const float*)d_in[o + 6];
        const float* bv  = (const float*)d_in[o + 7];
        k_gat_pre<<<N_NODES / 32, 256, 0, stream>>>(h, gw, asr, ads, bg, bb, bm, bv, g, asv, adv);
        k_maxl<<<N_NODES / 256, 256, 0, stream>>>(asv, rp, esrc, smax);
        k_aggr<<<N_NODES / 8, 256, 0, stream>>>(h, g, asv, adv, smax, rp, esrc, gbb);
    }

    // mem_pool 1 + kl
    k_mem1<<<N_NODES / 256, 256, 0, stream>>>(h, k1, conv1_w, S1, xo, cs);
    k_kl<<<N_NODES / 256, 256, 0, stream>>>(S1, cs, klg);

    // head
    k_head<<<NB, 128, 0, stream>>>(xo, lin1_w, lin1_b, lin2_w, lin2_b, klg, out);
}

// Round 5
// 448.855 us; speedup vs baseline: 1.8464x; 1.0882x over previous
//
#include <hip/hip_runtime.h>
#include <hip/hip_bf16.h>

#define N_NODES 131072
#define N_EDGES 2097152
#define NB 64
#define N_PER 2048
#define IN_CH 128
#define HID 32
#define NBKT 512            // buckets of 256 nodes each (bucket = dst >> 8)

__device__ __forceinline__ float leaky01(float v) { return v >= 0.0f ? v : 0.01f * v; }
__device__ __forceinline__ float leaky2(float v)  { return v >= 0.0f ? v : 0.2f  * v; }
__device__ __forceinline__ float bf2f(__hip_bfloat16 v) { return __bfloat162float(v); }

// ---- embed + GAT-pre layer1 fused:
// h = x@We + be;  t = leaky01(BN(h));  g1 = t@W1 (bf16);  asv=g1@a_src; adv=g1@a_dst
__global__ void k_embed_pre(const float* __restrict__ x, const float* __restrict__ We,
                            const float* __restrict__ be,
                            const float* __restrict__ W1, const float* __restrict__ a_src,
                            const float* __restrict__ a_dst,
                            const float* __restrict__ bn_g, const float* __restrict__ bn_b,
                            const float* __restrict__ bn_m, const float* __restrict__ bn_v,
                            float* __restrict__ h, __hip_bfloat16* __restrict__ g,
                            float* __restrict__ asv, float* __restrict__ adv) {
    __shared__ float4 sW4[IN_CH * HID / 4];   // 16 KB
    __shared__ float4 sx4[32 * IN_CH / 4];    // 16 KB
    __shared__ float st[32 * HID];            // 4 KB
    __shared__ float sW1[HID * HID];          // 4 KB
    __shared__ float ssc[HID], ssh[HID];
    int tid = threadIdx.x;
    if (tid < HID) {
        float sc = bn_g[tid] * rsqrtf(bn_v[tid] + 1e-5f);
        ssc[tid] = sc;
        ssh[tid] = bn_b[tid] - bn_m[tid] * sc;
    }
    const float4* W4 = (const float4*)We;
    for (int i = tid; i < IN_CH * HID / 4; i += 256) sW4[i] = W4[i];
    const float4* x4 = (const float4*)(x + (size_t)blockIdx.x * 32 * IN_CH);
    for (int i = tid; i < 32 * IN_CH / 4; i += 256) sx4[i] = x4[i];
    for (int i = tid; i < HID * HID; i += 256) sW1[i] = W1[i];
    __syncthreads();
    const float* sW = (const float*)sW4;
    const float* sx = (const float*)sx4;
    int r0 = tid >> 5, c = tid & 31;
    float b = be[c];
    float acc0 = b, acc1 = b, acc2 = b, acc3 = b;
    #pragma unroll
    for (int k = 0; k < IN_CH; ++k) {
        float w = sW[k * HID + c];
        acc0 += sx[(r0     ) * IN_CH + k] * w;
        acc1 += sx[(r0 +  8) * IN_CH + k] * w;
        acc2 += sx[(r0 + 16) * IN_CH + k] * w;
        acc3 += sx[(r0 + 24) * IN_CH + k] * w;
    }
    int base = blockIdx.x * 32 * HID;
    h[base + (r0     ) * HID + c] = acc0;
    h[base + (r0 +  8) * HID + c] = acc1;
    h[base + (r0 + 16) * HID + c] = acc2;
    h[base + (r0 + 24) * HID + c] = acc3;
    float sc = ssc[c], sh = ssh[c];
    st[(r0     ) * HID + c] = leaky01(acc0 * sc + sh);
    st[(r0 +  8) * HID + c] = leaky01(acc1 * sc + sh);
    st[(r0 + 16) * HID + c] = leaky01(acc2 * sc + sh);
    st[(r0 + 24) * HID + c] = leaky01(acc3 * sc + sh);
    __syncthreads();
    float as_c = a_src[c], ad_c = a_dst[c];
    float g0 = 0.f, g1 = 0.f, g2 = 0.f, g3 = 0.f;
    #pragma unroll
    for (int k = 0; k < HID; ++k) {
        float w = sW1[k * HID + c];
        g0 += st[(r0     ) * HID + k] * w;
        g1 += st[(r0 +  8) * HID + k] * w;
        g2 += st[(r0 + 16) * HID + k] * w;
        g3 += st[(r0 + 24) * HID + k] * w;
    }
    g[base + (r0     ) * HID + c] = __float2bfloat16(g0);
    g[base + (r0 +  8) * HID + c] = __float2bfloat16(g1);
    g[base + (r0 + 16) * HID + c] = __float2bfloat16(g2);
    g[base + (r0 + 24) * HID + c] = __float2bfloat16(g3);
    float p0 = g0 * as_c, p1 = g1 * as_c, p2 = g2 * as_c, p3 = g3 * as_c;
    float q0 = g0 * ad_c, q1 = g1 * ad_c, q2 = g2 * ad_c, q3 = g3 * ad_c;
    #pragma unroll
    for (int m = 16; m >= 1; m >>= 1) {
        p0 += __shfl_xor(p0, m); p1 += __shfl_xor(p1, m);
        p2 += __shfl_xor(p2, m); p3 += __shfl_xor(p3, m);
        q0 += __shfl_xor(q0, m); q1 += __shfl_xor(q1, m);
        q2 += __shfl_xor(q2, m); q3 += __shfl_xor(q3, m);
    }
    if (c == 0) {
        int row = blockIdx.x * 32 + r0;
        asv[row     ] = p0;  adv[row     ] = q0;
        asv[row +  8] = p1;  adv[row +  8] = q1;
        asv[row + 16] = p2;  adv[row + 16] = q2;
        asv[row + 24] = p3;  adv[row + 24] = q3;
    }
}

// ---------------- CSR build (bucketed counting sort) ----------------
__global__ void kb_count(const int* __restrict__ ei, int* __restrict__ bcnt) {
    __shared__ int hist[NBKT];
    int tid = threadIdx.x;
    hist[tid] = 0; hist[tid + 256] = 0;
    __syncthreads();
    int e0 = blockIdx.x * 8192;
    #pragma unroll 4
    for (int k = 0; k < 32; ++k) {
        int d = ei[N_EDGES + e0 + k * 256 + tid];
        atomicAdd(&hist[d >> 8], 1);
    }
    __syncthreads();
    atomicAdd(&bcnt[tid], hist[tid]);
    atomicAdd(&bcnt[tid + 256], hist[tid + 256]);
}

__global__ void kb_bscan(const int* __restrict__ bcnt, int* __restrict__ bbase,
                         int* __restrict__ bcur) {
    __shared__ int s[NBKT];
    int tid = threadIdx.x;
    int v = bcnt[tid];
    s[tid] = v; __syncthreads();
    for (int off = 1; off < NBKT; off <<= 1) {
        int t = (tid >= off) ? s[tid - off] : 0;
        __syncthreads();
        s[tid] += t;
        __syncthreads();
    }
    int ex = s[tid] - v;
    bbase[tid] = ex;
    bcur[tid] = ex;
}

__global__ void kb_scatter(const int* __restrict__ ei, int* __restrict__ bcur,
                           unsigned int* __restrict__ pk) {
    __shared__ int hist[NBKT];
    __shared__ int base[NBKT];
    int tid = threadIdx.x;
    hist[tid] = 0; hist[tid + 256] = 0;
    __syncthreads();
    int e0 = blockIdx.x * 8192;
    #pragma unroll 4
    for (int k = 0; k < 32; ++k) {
        int d = ei[N_EDGES + e0 + k * 256 + tid];
        atomicAdd(&hist[d >> 8], 1);
    }
    __syncthreads();
    base[tid] = atomicAdd(&bcur[tid], hist[tid]);
    base[tid + 256] = atomicAdd(&bcur[tid + 256], hist[tid + 256]);
    __syncthreads();
    hist[tid] = 0; hist[tid + 256] = 0;
    __syncthreads();
    for (int k = 0; k < 32; ++k) {
        int e = e0 + k * 256 + tid;
        int d = ei[N_EDGES + e];
        int s = ei[e];
        int b = d >> 8;
        int loc = atomicAdd(&hist[b], 1);
        pk[base[b] + loc] = (unsigned int)s | ((unsigned int)(d & 255) << 17);
    }
}

// per-bucket node histogram + in-block scan -> rp directly (bbase[b] == rp of first node)
__global__ void kb_hist(const unsigned int* __restrict__ pk, const int* __restrict__ bcnt,
                        const int* __restrict__ bbase, int* __restrict__ rp) {
    __shared__ int lc[256];
    __shared__ int sc[256];
    int b = blockIdx.x, tid = threadIdx.x;
    lc[tid] = 0; __syncthreads();
    int n = bcnt[b], base = bbase[b];
    for (int i = tid; i < n; i += 256) atomicAdd(&lc[pk[base + i] >> 17], 1);
    __syncthreads();
    int v = lc[tid];
    sc[tid] = v; __syncthreads();
    for (int off = 1; off < 256; off <<= 1) {
        int t = (tid >= off) ? sc[tid - off] : 0;
        __syncthreads();
        sc[tid] += t;
        __syncthreads();
    }
    rp[b * 256 + tid] = base + sc[tid] - v;
    if (b == NBKT - 1 && tid == 255) rp[N_NODES] = N_EDGES;
}

__global__ void kb_fill(const unsigned int* __restrict__ pk, const int* __restrict__ bcnt,
                        const int* __restrict__ bbase, const int* __restrict__ rp,
                        int* __restrict__ esrc) {
    __shared__ int lcur[256];
    int b = blockIdx.x, tid = threadIdx.x;
    lcur[tid] = rp[b * 256 + tid];
    __syncthreads();
    int n = bcnt[b], base = bbase[b];
    for (int i = tid; i < n; i += 256) {
        unsigned int v = pk[base + i];
        int pos = atomicAdd(&lcur[v >> 17], 1);
        esrc[pos] = (int)(v & 0x1FFFFu);
    }
}

// ------- GAT pre (layer 2): t = leaky(BN(h)); g = t@W (bf16); asv/adv -------
__global__ void k_gat_pre(const float* __restrict__ h, const float* __restrict__ W,
                          const float* __restrict__ a_src, const float* __restrict__ a_dst,
                          const float* __restrict__ bn_g, const float* __restrict__ bn_b,
                          const float* __restrict__ bn_m, const float* __restrict__ bn_v,
                          __hip_bfloat16* __restrict__ g, float* __restrict__ asv,
                          float* __restrict__ adv) {
    __shared__ float sW[HID * HID];
    __shared__ float st[32 * HID];
    __shared__ float ssc[HID], ssh[HID];
    int tid = threadIdx.x;
    if (tid < HID) {
        float sc = bn_g[tid] * rsqrtf(bn_v[tid] + 1e-5f);
        ssc[tid] = sc;
        ssh[tid] = bn_b[tid] - bn_m[tid] * sc;
    }
    for (int i = tid; i < HID * HID; i += 256) sW[i] = W[i];
    __syncthreads();
    int base = blockIdx.x * 32 * HID;
    for (int i = tid; i < 32 * HID; i += 256) {
        int ch = i & 31;
        st[i] = leaky01(h[base + i] * ssc[ch] + ssh[ch]);
    }
    __syncthreads();
    int r0 = tid >> 5, c = tid & 31;
    float as_c = a_src[c], ad_c = a_dst[c];
    float g0 = 0.f, g1 = 0.f, g2 = 0.f, g3 = 0.f;
    #pragma unroll
    for (int k = 0; k < HID; ++k) {
        float w = sW[k * HID + c];
        g0 += st[(r0     ) * HID + k] * w;
        g1 += st[(r0 +  8) * HID + k] * w;
        g2 += st[(r0 + 16) * HID + k] * w;
        g3 += st[(r0 + 24) * HID + k] * w;
    }
    g[base + (r0     ) * HID + c] = __float2bfloat16(g0);
    g[base + (r0 +  8) * HID + c] = __float2bfloat16(g1);
    g[base + (r0 + 16) * HID + c] = __float2bfloat16(g2);
    g[base + (r0 + 24) * HID + c] = __float2bfloat16(g3);
    float p0 = g0 * as_c, p1 = g1 * as_c, p2 = g2 * as_c, p3 = g3 * as_c;
    float q0 = g0 * ad_c, q1 = g1 * ad_c, q2 = g2 * ad_c, q3 = g3 * ad_c;
    #pragma unroll
    for (int m = 16; m >= 1; m >>= 1) {
        p0 += __shfl_xor(p0, m); p1 += __shfl_xor(p1, m);
        p2 += __shfl_xor(p2, m); p3 += __shfl_xor(p3, m);
        q0 += __shfl_xor(q0, m); q1 += __shfl_xor(q1, m);
        q2 += __shfl_xor(q2, m); q3 += __shfl_xor(q3, m);
    }
    if (c == 0) {
        int row = blockIdx.x * 32 + r0;
        asv[row     ] = p0;  adv[row     ] = q0;
        asv[row +  8] = p1;  adv[row +  8] = q1;
        asv[row + 16] = p2;  adv[row + 16] = q2;
        asv[row + 24] = p3;  adv[row + 24] = q3;
    }
}

// ------- GAT aggregate: lane-parallel logits, broadcast FMA, no max (shift-invariant) -------
__global__ void k_aggr(float* __restrict__ h, const __hip_bfloat16* __restrict__ g,
                       const float* __restrict__ asv, const float* __restrict__ adv,
                       const int* __restrict__ rp, const int* __restrict__ esrc,
                       const float* __restrict__ gbias) {
    int node = blockIdx.x * 8 + (threadIdx.x >> 5);
    int lane = threadIdx.x & 31;
    float ad_i = adv[node];
    float e_self = __expf(leaky2(asv[node] + ad_i));
    float z = e_self;
    float acc = e_self * bf2f(g[node * HID + lane]);
    int beg = rp[node], end = rp[node + 1];
    for (int jb = beg; jb < end; jb += 32) {
        int j = jb + lane;
        int s = 0; float e = 0.0f;
        if (j < end) {
            s = esrc[j];
            e = __expf(leaky2(asv[s] + ad_i));
        }
        float zs = e;
        #pragma unroll
        for (int mm = 16; mm >= 1; mm >>= 1) zs += __shfl_xor(zs, mm);
        z += zs;
        int cnt = end - jb; if (cnt > 32) cnt = 32;
        int jj = 0;
        for (; jj + 4 <= cnt; jj += 4) {
            int s0 = __shfl(s, jj, 32), s1 = __shfl(s, jj + 1, 32);
            int s2 = __shfl(s, jj + 2, 32), s3 = __shfl(s, jj + 3, 32);
            float e0 = __shfl(e, jj, 32), e1 = __shfl(e, jj + 1, 32);
            float e2 = __shfl(e, jj + 2, 32), e3 = __shfl(e, jj + 3, 32);
            float g0 = bf2f(g[s0 * HID + lane]);
            float g1 = bf2f(g[s1 * HID + lane]);
            float g2 = bf2f(g[s2 * HID + lane]);
            float g3 = bf2f(g[s3 * HID + lane]);
            acc += e0 * g0 + e1 * g1 + e2 * g2 + e3 * g3;
        }
        for (; jj < cnt; ++jj) {
            int ss = __shfl(s, jj, 32);
            float ee = __shfl(e, jj, 32);
            acc += ee * bf2f(g[ss * HID + lane]);
        }
    }
    h[node * HID + lane] += acc / (z + 1e-16f) + gbias[lane];
}

// ------- mem_pool 1: S1 [N,10], colsum [B,10], xo partial [B,10,32] -------
__global__ void k_mem1(const float* __restrict__ h, const float* __restrict__ k1,
                       const float* __restrict__ conv_w,
                       float* __restrict__ S1, float* __restrict__ xo,
                       float* __restrict__ colsum) {
    __shared__ float sh[256 * 33];        // 33 KB, padded h slab
    __shared__ float sk1[5 * 10 * HID];   // 6.4 KB
    __shared__ float sk2[50];
    __shared__ float scw[5];
    __shared__ float s1l[256][10];        // 10 KB
    int tid = threadIdx.x;
    for (int i = tid; i < 5 * 10 * HID; i += 256) sk1[i] = k1[i];
    if (tid < 5) scw[tid] = conv_w[tid];
    const float4* hp = (const float4*)(h + (size_t)blockIdx.x * 256 * HID);
    for (int i = tid; i < 2048; i += 256) {
        float4 v = hp[i];
        int row = i >> 3, c4 = (i & 7) * 4;
        float* dst = &sh[row * 33 + c4];
        dst[0] = v.x; dst[1] = v.y; dst[2] = v.z; dst[3] = v.w;
    }
    __syncthreads();
    if (tid < 50) {
        float s = 0.0f;
        for (int f = 0; f < HID; ++f) { float t = sk1[tid * HID + f]; s += t * t; }
        sk2[tid] = s;
    }
    __syncthreads();

    int nid = blockIdx.x * 256 + tid;
    float xr[HID];
    #pragma unroll
    for (int f = 0; f < HID; ++f) xr[f] = sh[tid * 33 + f];
    float x2n = 0.0f;
    #pragma unroll
    for (int f = 0; f < HID; ++f) x2n += xr[f] * xr[f];

    float Sc[10];
    #pragma unroll
    for (int k = 0; k < 10; ++k) Sc[k] = 0.0f;

    for (int hh = 0; hh < 5; ++hh) {
        float tmp[10];
        float rsum = 0.0f;
        #pragma unroll
        for (int k = 0; k < 10; ++k) {
            float dot = 0.0f;
            #pragma unroll
            for (int f = 0; f < HID; ++f) dot += xr[f] * sk1[(hh * 10 + k) * HID + f];
            float d = x2n + sk2[hh * 10 + k] - 2.0f * dot;
            d = d > 0.0f ? d : 0.0f;
            float s = 1.0f / (1.0f + d);
            tmp[k] = s;
            rsum += s;
        }
        float w = scw[hh] / rsum;
        #pragma unroll
        for (int k = 0; k < 10; ++k) Sc[k] += tmp[k] * w;
    }
    float mx = Sc[0];
    #pragma unroll
    for (int k = 1; k < 10; ++k) mx = fmaxf(mx, Sc[k]);
    float se = 0.0f;
    #pragma unroll
    for (int k = 0; k < 10; ++k) { float e = __expf(Sc[k] - mx); Sc[k] = e; se += e; }
    float inv = 1.0f / se;
    #pragma unroll
    for (int k = 0; k < 10; ++k) {
        float v = Sc[k] * inv;
        s1l[tid][k] = v;
        S1[nid * 10 + k] = v;
    }
    __syncthreads();

    int b = nid >> 11;
    for (int idx = tid; idx < 320; idx += 256) {
        int k = idx >> 5, f = idx & 31;
        float s = 0.0f;
        #pragma unroll 4
        for (int n = 0; n < 256; ++n) s += s1l[n][k] * sh[n * 33 + f];
        atomicAdd(&xo[(b * 10 + k) * HID + f], s);
    }
    for (int k = tid; k < 10; k += 256) {
        float s = 0.0f;
        for (int n = 0; n < 256; ++n) s += s1l[n][k];
        atomicAdd(&colsum[b * 10 + k], s);
    }
}

// ------- kl_loss(S1) accumulation -------
__global__ void k_kl(const float* __restrict__ S1, const float* __restrict__ colsum,
                     float* __restrict__ klg) {
    __shared__ float red[256];
    int tid = threadIdx.x;
    int nid = blockIdx.x * 256 + tid;
    int b = nid >> 11;
    const float* srow = S1 + nid * 10;
    float p[10], sv[10];
    float dsum = 0.0f;
    #pragma unroll
    for (int k = 0; k < 10; ++k) {
        float s = srow[k];
        sv[k] = s;
        float pk = s * s / fmaxf(colsum[b * 10 + k], 1e-15f);
        p[k] = pk;
        dsum += pk;
    }
    float invd = 1.0f / dsum;
    float term = 0.0f;
    #pragma unroll
    for (int k = 0; k < 10; ++k) {
        float pk = fmaxf(p[k] * invd, 1e-15f);
        float s = fmaxf(sv[k], 1e-15f);
        term += pk * (logf(pk) - logf(s));
    }
    red[tid] = term; __syncthreads();
    for (int off = 128; off > 0; off >>= 1) {
        if (tid < off) red[tid] += red[tid + off];
        __syncthreads();
    }
    if (tid == 0) atomicAdd(klg, red[0]);
}

// ------- head -------
__global__ void k_head(const float* __restrict__ xo, const float* __restrict__ l1w,
                       const float* __restrict__ l1b, const float* __restrict__ l2w,
                       const float* __restrict__ l2b, const float* __restrict__ klg,
                       float* __restrict__ out) {
    __shared__ float sxo[320];
    __shared__ float s80[80];
    __shared__ float lg[10];
    int b = blockIdx.x, tid = threadIdx.x;
    for (int i = tid; i < 320; i += 128) sxo[i] = xo[b * 320 + i];
    __syncthreads();
    if (tid < 80) {
        float s = 0.0f;
        for (int k = 0; k < 10; ++k) {
            float a = l1b[tid];
            #pragma unroll
            for (int i = 0; i < HID; ++i) a += sxo[k * HID + i] * l1w[i * 80 + tid];
            s += leaky01(a);
        }
        s80[tid] = s;
    }
    __syncthreads();
    if (tid < 10) {
        float a = l2b[tid];
        for (int f = 0; f < 80; ++f) a += s80[f] * l2w[f * 10 + tid];
        lg[tid] = leaky01(a);
    }
    __syncthreads();
    if (tid == 0) {
        float m = lg[0];
        for (int j = 1; j < 10; ++j) m = fmaxf(m, lg[j]);
        float se = 0.0f;
        for (int j = 0; j < 10; ++j) se += expf(lg[j] - m);
        float ls = logf(se);
        for (int j = 0; j < 10; ++j) out[b * 10 + j] = lg[j] - m - ls;
        if (b == 0) out[640] = klg[0] * (1.0f / 64.0f);
    }
}

extern "C" void kernel_launch(void* const* d_in, const int* in_sizes, int n_in,
                              void* d_out, int out_size, void* d_ws, size_t ws_size,
                              hipStream_t stream) {
    const float* x       = (const float*)d_in[0];
    const int*   ei      = (const int*)d_in[1];
    const float* w_embed = (const float*)d_in[3];
    const float* b_embed = (const float*)d_in[4];
    const float* k1      = (const float*)d_in[21];
    const float* conv1_w = (const float*)d_in[22];
    const float* lin1_w  = (const float*)d_in[23];
    const float* lin1_b  = (const float*)d_in[24];
    const float* lin2_w  = (const float*)d_in[27];
    const float* lin2_b  = (const float*)d_in[28];
    float* out = (float*)d_out;

    char* w = (char*)d_ws;
    float*          h    = (float*)(w + 0);                 // 16,777,216
    __hip_bfloat16* g    = (__hip_bfloat16*)(w + 16777216); //  8,388,608
    unsigned int*   pk   = (unsigned int*)(w + 25165824);   //  8,388,608
    int*            esrc = (int*)(w + 33554432);            //  8,388,608
    float*          asv  = (float*)(w + 41943040);          //    524,288
    float*          adv  = (float*)(w + 42467328);          //    524,288
    int*            rp   = (int*)(w + 42991616);            //    524,544
    float*          S1   = (float*)(w + 43516160);          //  5,242,880
    int*            bbase= (int*)(w + 48759040);            //      2,048
    int*            bcur = (int*)(w + 48761088);            //      2,048
    int*            bcnt = (int*)(w + 48763136);            //      2,048  <- zero region start
    float*          xo   = (float*)(w + 48765184);          //     81,920
    float*          cs   = (float*)(w + 48847104);          //      2,560
    float*          klg  = (float*)(w + 48849664);          //          4

    hipMemsetAsync(bcnt, 0, 2048 + 81920 + 2560 + 4, stream);

    // embed + GAT-pre layer1 (fused)
    {
        const float* gw1  = (const float*)d_in[5];
        const float* asr1 = (const float*)d_in[6];
        const float* ads1 = (const float*)d_in[7];
        const float* bg1  = (const float*)d_in[9];
        const float* bb1  = (const float*)d_in[10];
        const float* bm1  = (const float*)d_in[11];
        const float* bv1  = (const float*)d_in[12];
        k_embed_pre<<<N_NODES / 32, 256, 0, stream>>>(x, w_embed, b_embed,
                                                      gw1, asr1, ads1,
                                                      bg1, bb1, bm1, bv1,
                                                      h, g, asv, adv);
    }

    // CSR by dst via 512-bucket counting sort (shared by both GAT layers)
    kb_count<<<N_EDGES / 8192, 256, 0, stream>>>(ei, bcnt);
    kb_bscan<<<1, NBKT, 0, stream>>>(bcnt, bbase, bcur);
    kb_scatter<<<N_EDGES / 8192, 256, 0, stream>>>(ei, bcur, pk);
    kb_hist<<<NBKT, 256, 0, stream>>>(pk, bcnt, bbase, rp);
    kb_fill<<<NBKT, 256, 0, stream>>>(pk, bcnt, bbase, rp, esrc);

    // layer1 aggregate
    k_aggr<<<N_NODES / 8, 256, 0, stream>>>(h, g, asv, adv, rp, esrc,
                                            (const float*)d_in[8]);

    // layer2 pre + aggregate
    k_gat_pre<<<N_NODES / 32, 256, 0, stream>>>(h,
                                                (const float*)d_in[13],
                                                (const float*)d_in[14],
                                                (const float*)d_in[15],
                                                (const float*)d_in[17],
                                                (const float*)d_in[18],
                                                (const float*)d_in[19],
                                                (const float*)d_in[20],
                                                g, asv, adv);
    k_aggr<<<N_NODES / 8, 256, 0, stream>>>(h, g, asv, adv, rp, esrc,
                                            (const float*)d_in[16]);

    // mem_pool 1 + kl
    k_mem1<<<N_NODES / 256, 256, 0, stream>>>(h, k1, conv1_w, S1, xo, cs);
    k_kl<<<N_NODES / 256, 256, 0, stream>>>(S1, cs, klg);

    // head
    k_head<<<NB, 128, 0, stream>>>(xo, lin1_w, lin1_b, lin2_w, lin2_b, klg, out);
}